// Round 6
// baseline (630.466 us; speedup 1.0000x reference)
//
#include <hip/hip_runtime.h>
#include <hip/hip_bf16.h>

// Two-pass bf16-MFMA attention with materialized attn.
// B=64, TQ=TK=1024, DK=DV=64.
//
// Pass 1 (prep): pure streaming —
//   - V -> V^T bf16 [b][d][k]   (1024 blocks)
//   - mask -> ballot-packed bits: per 256 consecutive keys, 4 x u64 where
//     bit l of word r = mask[g*256 + 4l + r]. Produced with coalesced int4
//     loads (1 KB/wave/instr) + 4 __ballot's (R5's version was fully
//     uncoalesced: lane-stride 128 B -> transaction-bound).
//   - Q -> bf16 (0.125 folded), K -> bf16
// Pass 2 (main): WG=256=4 waves, 16 queries/WG, wave w owns keys [w*256,+256).
//   S^T = mfma(K,Q). K loads batched 8 tiles deep and pinned with
//   sched_barrier(0) so the compiler cannot serialize them (R4/R5 VGPR=64
//   proved it sank all loads to just-before-use); tiles 8..15 refill the
//   same registers inside the MFMA loop (8 loads continuously in flight).
//   Mask via bit-extract from ballot words; V^T A-frags loaded directly;
//   P -> LDS in two 128-key halves (17920 B total LDS).
// Falls back to the R3 single-pass kernel if ws_size < 32 MiB.

#define B_   64
#define TQ_  1024
#define TK_  1024
#define DD   64

typedef short short8 __attribute__((ext_vector_type(8)));
typedef float f32x4 __attribute__((ext_vector_type(4)));

#define PLW    68              // u32 per P row: 64 data (128 keys bf16) + 4 pad
#define PL_U32 (16 * PLW)      // 1088 u32 = 4352 B per wave (P half / O stage)

// workspace layout
#define QB_OFF  (0u)
#define KB_OFF  (8u << 20)
#define VT_OFF  (16u << 20)
#define MB_OFF  (24u << 20)
#define WS_NEED (32u << 20)    // 33554432 B

__device__ __forceinline__ unsigned cvt2(float a, float b) {
    __hip_bfloat162 h = __float22bfloat162_rn(make_float2(a, b));
    unsigned u; __builtin_memcpy(&u, &h, 4); return u;
}
__device__ __forceinline__ short cvt1(float a) {
    __hip_bfloat16 h = __float2bfloat16(a);
    short s; __builtin_memcpy(&s, &h, 2); return s;
}

union Frag { short8 s; unsigned u[4]; };

// ============================ PREP PASS ============================
// grid: [0,1024) V^T | [1024,9216) mask-ballot | [9216,11264) Q | [11264,13312) K
__global__ __launch_bounds__(256) void prep_kernel(
    const float* __restrict__ qg, const float* __restrict__ kg,
    const float* __restrict__ vg, const int* __restrict__ maskg,
    unsigned char* __restrict__ ws)
{
    const int t = threadIdx.x;
    const int gid = blockIdx.x;
    if (gid < 1024) {
        // V^T for one (batch, 64-key tile): [64 k][64 d] f32 -> [64 d][64 k] bf16
        __shared__ short tl[64][72];
        const int b  = gid >> 4;
        const int k0 = (gid & 15) * 64;
        const float* vb = vg + (size_t)b * TK_ * DD;
        short* ob = (short*)(ws + VT_OFF) + (size_t)b * DD * TK_;
        #pragma unroll
        for (int i = 0; i < 4; ++i) {
            const int row = i * 16 + (t >> 4);
            const int d   = (t & 15) * 4;
            const float4 x = *(const float4*)(vb + (size_t)(k0 + row) * DD + d);
            tl[d + 0][row] = cvt1(x.x); tl[d + 1][row] = cvt1(x.y);
            tl[d + 2][row] = cvt1(x.z); tl[d + 3][row] = cvt1(x.w);
        }
        __syncthreads();
        #pragma unroll
        for (int p = 0; p < 2; ++p) {
            const int d = p * 32 + (t >> 3);
            const uint4 val = *(const uint4*)&tl[d][(t & 7) * 8];
            *(uint4*)(ob + (size_t)d * TK_ + k0 + (t & 7) * 8) = val;
        }
    } else if (gid < 1024 + 8192) {
        // ballot mask-pack: each wave handles 8 groups of 256 ints.
        // group g -> 4 x u64: bit l of word r = mask[g*256 + 4l + r] & 1
        const int blk = gid - 1024;
        const int w = t >> 6, l = t & 63;
        unsigned* mb = (unsigned*)(ws + MB_OFF);
        #pragma unroll
        for (int i = 0; i < 8; ++i) {
            const int g = blk * 32 + w * 8 + i;
            const int4 x = *(const int4*)(maskg + (size_t)g * 256 + 4 * l);
            const unsigned long long b0 = __ballot(x.x & 1);
            const unsigned long long b1 = __ballot(x.y & 1);
            const unsigned long long b2 = __ballot(x.z & 1);
            const unsigned long long b3 = __ballot(x.w & 1);
            if (l == 0) {
                uint4 o0, o1;
                o0.x = (unsigned)b0; o0.y = (unsigned)(b0 >> 32);
                o0.z = (unsigned)b1; o0.w = (unsigned)(b1 >> 32);
                o1.x = (unsigned)b2; o1.y = (unsigned)(b2 >> 32);
                o1.z = (unsigned)b3; o1.w = (unsigned)(b3 >> 32);
                *(uint4*)(mb + (size_t)g * 8)     = o0;
                *(uint4*)(mb + (size_t)g * 8 + 4) = o1;
            }
        }
    } else if (gid < 1024 + 8192 + 2048) {
        const int i8 = (gid - 1024 - 8192) * 256 + t;   // 8 floats per thread
        const float* p = qg + (size_t)i8 * 8;
        const float4 x = *(const float4*)p, y = *(const float4*)(p + 4);
        uint4 o;
        o.x = cvt2(0.125f * x.x, 0.125f * x.y); o.y = cvt2(0.125f * x.z, 0.125f * x.w);
        o.z = cvt2(0.125f * y.x, 0.125f * y.y); o.w = cvt2(0.125f * y.z, 0.125f * y.w);
        ((uint4*)(ws + QB_OFF))[i8] = o;
    } else {
        const int i8 = (gid - 1024 - 8192 - 2048) * 256 + t;
        const float* p = kg + (size_t)i8 * 8;
        const float4 x = *(const float4*)p, y = *(const float4*)(p + 4);
        uint4 o;
        o.x = cvt2(x.x, x.y); o.y = cvt2(x.z, x.w);
        o.z = cvt2(y.x, y.y); o.w = cvt2(y.z, y.w);
        ((uint4*)(ws + KB_OFF))[i8] = o;
    }
}

// ============================ MAIN PASS ============================
__global__ __launch_bounds__(256, 4) void attn_bf16_kernel(
    const unsigned char* __restrict__ ws,
    float* __restrict__ outg, float* __restrict__ attng)
{
    __shared__ __align__(16) unsigned lds[4 * PL_U32];   // 17408 B
    __shared__ float red[128];                           // total 17920 B

    const int t    = threadIdx.x;
    const int wave = t >> 6, lane = t & 63;
    const int quad = lane >> 4, n16 = lane & 15;
    const int b    = blockIdx.y;
    const int q0   = blockIdx.x * 16;
    const int kbase = wave * 256;

    const short*    Qb = (const short*)(ws + QB_OFF);
    const short*    Kb = (const short*)(ws + KB_OFF);
    const short*    Vt = (const short*)(ws + VT_OFF);
    const unsigned* Mb = (const unsigned*)(ws + MB_OFF);

    unsigned* pl = lds + wave * PL_U32;

    // ---- mask ballot words for (row q0+n16, key group = wave) ----
    const unsigned* mg = Mb + ((size_t)(b * TQ_ + q0 + n16) * 4 + wave) * 8;
    const uint4 M0 = *(const uint4*)(mg);      // {b0.lo,b0.hi,b1.lo,b1.hi}
    const uint4 M1 = *(const uint4*)(mg + 4);  // {b2.lo,b2.hi,b3.lo,b3.hi}

    // ---- Q frags (bf16, pre-scaled) ----
    const short* qp = Qb + ((size_t)(b * TQ_ + q0 + n16)) * DD + quad * 8;
    Frag qf0, qf1;
    qf0.s = *(const short8*)(qp);
    qf1.s = *(const short8*)(qp + 32);

    // ---- K tiles 0..7 batched up-front; sched_barrier pins early issue ----
    const short* kbp = Kb + (size_t)(b * TK_ + kbase) * DD;
    Frag kf[8][2];
    #pragma unroll
    for (int kt = 0; kt < 8; ++kt) {
        const short* kp = kbp + (size_t)(kt * 16 + n16) * DD + quad * 8;
        kf[kt][0].s = *(const short8*)(kp);
        kf[kt][1].s = *(const short8*)(kp + 32);
    }
    __builtin_amdgcn_sched_barrier(0);

    // ================= S^T = (K)(Q*0.125) + mask-bits =================
    float s_reg[64];  // s_reg[kt*4+r]: key kbase+kt*16+quad*4+r, query q0+n16
    #pragma unroll
    for (int kt = 0; kt < 8; ++kt) {
        f32x4 acc = {0.f, 0.f, 0.f, 0.f};
        acc = __builtin_amdgcn_mfma_f32_16x16x32_bf16(kf[kt][0].s, qf0.s, acc, 0, 0, 0);
        acc = __builtin_amdgcn_mfma_f32_16x16x32_bf16(kf[kt][1].s, qf1.s, acc, 0, 0, 0);
        // refill with tile kt+8 (rotates; keeps 8 loads in flight)
        {
            const short* kp = kbp + (size_t)((kt + 8) * 16 + n16) * DD + quad * 8;
            kf[kt][0].s = *(const short8*)(kp);
            kf[kt][1].s = *(const short8*)(kp + 32);
        }
        const unsigned sh = (unsigned)(kt * 4) + (unsigned)quad;   // < 32
        s_reg[kt * 4 + 0] = acc[0] + (((M0.x >> sh) & 1u) ? 0.f : -1e9f);
        s_reg[kt * 4 + 1] = acc[1] + (((M0.z >> sh) & 1u) ? 0.f : -1e9f);
        s_reg[kt * 4 + 2] = acc[2] + (((M1.x >> sh) & 1u) ? 0.f : -1e9f);
        s_reg[kt * 4 + 3] = acc[3] + (((M1.z >> sh) & 1u) ? 0.f : -1e9f);
    }
    #pragma unroll
    for (int kt = 8; kt < 16; ++kt) {
        f32x4 acc = {0.f, 0.f, 0.f, 0.f};
        acc = __builtin_amdgcn_mfma_f32_16x16x32_bf16(kf[kt - 8][0].s, qf0.s, acc, 0, 0, 0);
        acc = __builtin_amdgcn_mfma_f32_16x16x32_bf16(kf[kt - 8][1].s, qf1.s, acc, 0, 0, 0);
        const unsigned sh = (unsigned)((kt - 8) * 4) + (unsigned)quad;
        s_reg[kt * 4 + 0] = acc[0] + (((M0.y >> sh) & 1u) ? 0.f : -1e9f);
        s_reg[kt * 4 + 1] = acc[1] + (((M0.w >> sh) & 1u) ? 0.f : -1e9f);
        s_reg[kt * 4 + 2] = acc[2] + (((M1.y >> sh) & 1u) ? 0.f : -1e9f);
        s_reg[kt * 4 + 3] = acc[3] + (((M1.w >> sh) & 1u) ? 0.f : -1e9f);
    }

    // ================= softmax =================
    float m8[8];
    #pragma unroll
    for (int j = 0; j < 8; ++j) m8[j] = s_reg[j];
    #pragma unroll
    for (int i = 8; i < 64; i += 8)
        #pragma unroll
        for (int j = 0; j < 8; ++j) m8[j] = fmaxf(m8[j], s_reg[i + j]);
    float m = fmaxf(fmaxf(fmaxf(m8[0], m8[1]), fmaxf(m8[2], m8[3])),
                    fmaxf(fmaxf(m8[4], m8[5]), fmaxf(m8[6], m8[7])));
    m = fmaxf(m, __shfl_xor(m, 16));
    m = fmaxf(m, __shfl_xor(m, 32));
    if (lane < 16) red[wave * 16 + n16] = m;
    __syncthreads();
    const float gm = fmaxf(fmaxf(red[n16], red[16 + n16]),
                           fmaxf(red[32 + n16], red[48 + n16]));
    float l0 = 0.f, l1 = 0.f, l2 = 0.f, l3 = 0.f;
    #pragma unroll
    for (int i = 0; i < 16; ++i) {
        const float p0 = __expf(s_reg[4*i+0] - gm);
        const float p1 = __expf(s_reg[4*i+1] - gm);
        const float p2 = __expf(s_reg[4*i+2] - gm);
        const float p3 = __expf(s_reg[4*i+3] - gm);
        s_reg[4*i+0] = p0; s_reg[4*i+1] = p1;
        s_reg[4*i+2] = p2; s_reg[4*i+3] = p3;
        l0 += p0; l1 += p1; l2 += p2; l3 += p3;
    }
    float lsum = (l0 + l1) + (l2 + l3);
    lsum += __shfl_xor(lsum, 16);
    lsum += __shfl_xor(lsum, 32);
    if (lane < 16) red[64 + wave * 16 + n16] = lsum;
    __syncthreads();
    const float inv = 1.f / (red[64 + n16] + red[80 + n16] +
                             red[96 + n16] + red[112 + n16]);
    #pragma unroll
    for (int i = 0; i < 64; ++i) s_reg[i] *= inv;

    // ---- V chunk-0 A-frags (issue before attn stores; hide under them) ----
    const short* vrow = Vt + (size_t)b * DD * TK_ + (size_t)n16 * TK_ + kbase + quad * 8;
    Frag vf[4];
    #pragma unroll
    for (int dg = 0; dg < 4; ++dg)
        vf[dg].s = *(const short8*)(vrow + (size_t)(dg * 16) * TK_);

    // ---- attn: 16 x float4 stores; pack LOW 128 keys (bf16) into P-LDS ----
    float* ab = attng + ((size_t)(b * TQ_ + q0 + n16)) * TK_ + kbase + quad * 4;
    #pragma unroll
    for (int kt = 0; kt < 16; ++kt)
        *(float4*)(ab + kt * 16) = make_float4(s_reg[kt*4+0], s_reg[kt*4+1],
                                               s_reg[kt*4+2], s_reg[kt*4+3]);
    #pragma unroll
    for (int kt = 0; kt < 8; ++kt) {
        uint2 u;
        u.x = cvt2(s_reg[kt*4+0], s_reg[kt*4+1]);
        u.y = cvt2(s_reg[kt*4+2], s_reg[kt*4+3]);
        *(uint2*)&pl[n16 * PLW + kt * 8 + quad * 2] = u;
    }

    // ================= O^T = (V^T)(P^T), V^T frags direct =================
    f32x4 oacc[4];
    #pragma unroll
    for (int dg = 0; dg < 4; ++dg) oacc[dg] = (f32x4){0.f, 0.f, 0.f, 0.f};

    #pragma unroll
    for (int c = 0; c < 4; ++c) {          // key chunks 0..3 (low P half)
        Frag cur[4];
        #pragma unroll
        for (int dg = 0; dg < 4; ++dg) cur[dg] = vf[dg];
        #pragma unroll
        for (int dg = 0; dg < 4; ++dg)
            vf[dg].s = *(const short8*)(vrow + (size_t)(dg * 16) * TK_ + (c + 1) * 32);
        Frag pf;
        pf.s = *(const short8*)&pl[n16 * PLW + c * 16 + quad * 4];
        #pragma unroll
        for (int dg = 0; dg < 4; ++dg)
            oacc[dg] = __builtin_amdgcn_mfma_f32_16x16x32_bf16(cur[dg].s, pf.s, oacc[dg], 0, 0, 0);
    }

    // pack HIGH 128 keys (reads of low half already issued; same-wave DS in-order)
    #pragma unroll
    for (int kt = 8; kt < 16; ++kt) {
        uint2 u;
        u.x = cvt2(s_reg[kt*4+0], s_reg[kt*4+1]);
        u.y = cvt2(s_reg[kt*4+2], s_reg[kt*4+3]);
        *(uint2*)&pl[n16 * PLW + (kt - 8) * 8 + quad * 2] = u;
    }

    #pragma unroll
    for (int c = 0; c < 4; ++c) {          // key chunks 4..7 (high P half)
        Frag cur[4];
        #pragma unroll
        for (int dg = 0; dg < 4; ++dg) cur[dg] = vf[dg];
        if (c < 3) {
            #pragma unroll
            for (int dg = 0; dg < 4; ++dg)
                vf[dg].s = *(const short8*)(vrow + (size_t)(dg * 16) * TK_ + (c + 5) * 32);
        }
        Frag pf;
        pf.s = *(const short8*)&pl[n16 * PLW + c * 16 + quad * 4];
        #pragma unroll
        for (int dg = 0; dg < 4; ++dg)
            oacc[dg] = __builtin_amdgcn_mfma_f32_16x16x32_bf16(cur[dg].s, pf.s, oacc[dg], 0, 0, 0);
    }

    // ---- cross-wave O reduction (stage O^T f32 in own P region) ----
    float* ow = (float*)pl;
    #pragma unroll
    for (int dg = 0; dg < 4; ++dg)
        *(f32x4*)&ow[n16 * PLW + dg * 16 + quad * 4] = oacc[dg];
    __syncthreads();
    {
        const int row = t >> 4, col = (t & 15) * 4;
        const float* base = (const float*)lds;
        float4 o = make_float4(0.f, 0.f, 0.f, 0.f);
        #pragma unroll
        for (int w = 0; w < 4; ++w) {
            const float4 x = *(const float4*)(base + w * PL_U32 + row * PLW + col);
            o.x += x.x; o.y += x.y; o.z += x.z; o.w += x.w;
        }
        *(float4*)(outg + ((size_t)(b * TQ_ + q0 + row)) * DD + col) = o;
    }
}

// ===================== FALLBACK (R3, verified) =====================
#define PSTR 264
#define FWVS (16 * PSTR)

__global__ __launch_bounds__(256, 3) void attn_fallback_kernel(
    const float* __restrict__ qg, const float* __restrict__ kg,
    const float* __restrict__ vg, const int* __restrict__ maskg,
    float* __restrict__ outg, float* __restrict__ attng)
{
    __shared__ __align__(16) short lds[4 * FWVS];
    __shared__ float red[128];

    const int t    = threadIdx.x;
    const int wave = t >> 6, lane = t & 63;
    const int quad = lane >> 4, n16 = lane & 15;
    const int b    = blockIdx.y;
    const int q0   = blockIdx.x * 16;
    const int kbase = wave * 256;

    short* pw = lds + wave * FWVS;

    Frag aq[2];
    {
        const float* qp = qg + ((size_t)(b * TQ_ + q0 + n16)) * DD + quad * 8;
        #pragma unroll
        for (int f = 0; f < 2; ++f) {
            float4 x = *(const float4*)(qp + f * 32);
            float4 y = *(const float4*)(qp + f * 32 + 4);
            aq[f].u[0] = cvt2(0.125f * x.x, 0.125f * x.y);
            aq[f].u[1] = cvt2(0.125f * x.z, 0.125f * x.w);
            aq[f].u[2] = cvt2(0.125f * y.x, 0.125f * y.y);
            aq[f].u[3] = cvt2(0.125f * y.z, 0.125f * y.w);
        }
    }

    float s_reg[64];
    const float* kbp  = kg + (size_t)b * TK_ * DD;
    const int*   mrow = maskg + ((size_t)(b * TQ_ + q0 + n16)) * TK_ + kbase + quad * 4;
    #pragma unroll
    for (int h = 0; h < 2; ++h) {
        int4 mk[8];
        #pragma unroll
        for (int i = 0; i < 8; ++i)
            mk[i] = *(const int4*)(mrow + (h * 8 + i) * 16);
        #pragma unroll
        for (int i = 0; i < 8; ++i) {
            const int kt = h * 8 + i;
            const float* kp = kbp + (size_t)(kbase + kt * 16 + n16) * DD + quad * 8;
            Frag bk[2];
            #pragma unroll
            for (int f = 0; f < 2; ++f) {
                float4 x = *(const float4*)(kp + f * 32);
                float4 y = *(const float4*)(kp + f * 32 + 4);
                bk[f].u[0] = cvt2(x.x, x.y); bk[f].u[1] = cvt2(x.z, x.w);
                bk[f].u[2] = cvt2(y.x, y.y); bk[f].u[3] = cvt2(y.z, y.w);
            }
            f32x4 acc = {0.f, 0.f, 0.f, 0.f};
            acc = __builtin_amdgcn_mfma_f32_16x16x32_bf16(bk[0].s, aq[0].s, acc, 0, 0, 0);
            acc = __builtin_amdgcn_mfma_f32_16x16x32_bf16(bk[1].s, aq[1].s, acc, 0, 0, 0);
            s_reg[kt * 4 + 0] = acc[0] + (mk[i].x ? 0.f : -1e9f);
            s_reg[kt * 4 + 1] = acc[1] + (mk[i].y ? 0.f : -1e9f);
            s_reg[kt * 4 + 2] = acc[2] + (mk[i].z ? 0.f : -1e9f);
            s_reg[kt * 4 + 3] = acc[3] + (mk[i].w ? 0.f : -1e9f);
        }
    }

    const float* vb0 = vg + (size_t)b * TK_ * DD + (size_t)(kbase + quad * 8) * DD + n16;
    float vraw[32];
    #pragma unroll
    for (int u = 0; u < 32; ++u)
        vraw[u] = vb0[(size_t)(u & 7) * DD + (u >> 3) * 16];

    float m8[8];
    #pragma unroll
    for (int j = 0; j < 8; ++j) m8[j] = s_reg[j];
    #pragma unroll
    for (int i = 8; i < 64; i += 8)
        #pragma unroll
        for (int j = 0; j < 8; ++j) m8[j] = fmaxf(m8[j], s_reg[i + j]);
    float m = fmaxf(fmaxf(fmaxf(m8[0], m8[1]), fmaxf(m8[2], m8[3])),
                    fmaxf(fmaxf(m8[4], m8[5]), fmaxf(m8[6], m8[7])));
    m = fmaxf(m, __shfl_xor(m, 16));
    m = fmaxf(m, __shfl_xor(m, 32));
    if (lane < 16) red[wave * 16 + n16] = m;
    __syncthreads();
    const float gm = fmaxf(fmaxf(red[n16], red[16 + n16]),
                           fmaxf(red[32 + n16], red[48 + n16]));
    float l0 = 0.f, l1 = 0.f, l2 = 0.f, l3 = 0.f;
    #pragma unroll
    for (int i = 0; i < 16; ++i) {
        const float p0 = __expf(s_reg[4*i+0] - gm);
        const float p1 = __expf(s_reg[4*i+1] - gm);
        const float p2 = __expf(s_reg[4*i+2] - gm);
        const float p3 = __expf(s_reg[4*i+3] - gm);
        s_reg[4*i+0] = p0; s_reg[4*i+1] = p1;
        s_reg[4*i+2] = p2; s_reg[4*i+3] = p3;
        l0 += p0; l1 += p1; l2 += p2; l3 += p3;
    }
    float lsum = (l0 + l1) + (l2 + l3);
    lsum += __shfl_xor(lsum, 16);
    lsum += __shfl_xor(lsum, 32);
    if (lane < 16) red[64 + wave * 16 + n16] = lsum;
    __syncthreads();
    const float inv = 1.f / (red[64 + n16] + red[80 + n16] +
                             red[96 + n16] + red[112 + n16]);
    #pragma unroll
    for (int i = 0; i < 64; ++i) s_reg[i] *= inv;

    float* ab = attng + ((size_t)(b * TQ_ + q0 + n16)) * TK_ + kbase + quad * 4;
    #pragma unroll
    for (int kt = 0; kt < 16; ++kt)
        *(float4*)(ab + kt * 16) = make_float4(s_reg[kt*4+0], s_reg[kt*4+1],
                                               s_reg[kt*4+2], s_reg[kt*4+3]);
    #pragma unroll
    for (int kt = 0; kt < 16; ++kt) {
        uint2 u;
        u.x = cvt2(s_reg[kt*4+0], s_reg[kt*4+1]);
        u.y = cvt2(s_reg[kt*4+2], s_reg[kt*4+3]);
        *(uint2*)(pw + n16 * PSTR + kt * 16 + quad * 4) = u;
    }

    f32x4 oacc[4];
    #pragma unroll
    for (int dg = 0; dg < 4; ++dg) oacc[dg] = (f32x4){0.f, 0.f, 0.f, 0.f};

    #pragma unroll
    for (int c = 0; c < 8; ++c) {
        unsigned va16[16];
        #pragma unroll
        for (int dg = 0; dg < 4; ++dg)
            #pragma unroll
            for (int w = 0; w < 4; ++w)
                va16[dg * 4 + w] = cvt2(vraw[dg * 8 + 2 * w], vraw[dg * 8 + 2 * w + 1]);
        if (c < 7) {
            #pragma unroll
            for (int u = 0; u < 32; ++u)
                vraw[u] = vb0[(size_t)((c + 1) * 32 + (u & 7)) * DD + (u >> 3) * 16];
        }
        Frag pf;
        pf.s = *(const short8*)(pw + n16 * PSTR + c * 32 + quad * 8);
        #pragma unroll
        for (int dg = 0; dg < 4; ++dg) {
            Frag af;
            af.u[0] = va16[dg*4+0]; af.u[1] = va16[dg*4+1];
            af.u[2] = va16[dg*4+2]; af.u[3] = va16[dg*4+3];
            oacc[dg] = __builtin_amdgcn_mfma_f32_16x16x32_bf16(af.s, pf.s, oacc[dg], 0, 0, 0);
        }
    }

    float* ow = (float*)pw;
    #pragma unroll
    for (int dg = 0; dg < 4; ++dg)
        *(f32x4*)&ow[n16 * 68 + dg * 16 + quad * 4] = oacc[dg];
    __syncthreads();
    {
        const int row = t >> 4, col = (t & 15) * 4;
        const float* base = (const float*)lds;
        float4 o = make_float4(0.f, 0.f, 0.f, 0.f);
        #pragma unroll
        for (int w = 0; w < 4; ++w) {
            const float4 x = *(const float4*)(base + w * (FWVS / 2) + row * 68 + col);
            o.x += x.x; o.y += x.y; o.z += x.z; o.w += x.w;
        }
        *(float4*)(outg + ((size_t)(b * TQ_ + q0 + row)) * DD + col) = o;
    }
}

extern "C" void kernel_launch(void* const* d_in, const int* in_sizes, int n_in,
                              void* d_out, int out_size, void* d_ws, size_t ws_size,
                              hipStream_t stream) {
    const float* q    = (const float*)d_in[0];
    const float* k    = (const float*)d_in[1];
    const float* v    = (const float*)d_in[2];
    const int*   mask = (const int*)d_in[3];

    float* out  = (float*)d_out;                   // [64][1024][64]
    float* attn = out + (size_t)B_ * TQ_ * DD;     // [64][1024][1024]

    if (ws_size >= (size_t)WS_NEED && d_ws != nullptr) {
        unsigned char* ws = (unsigned char*)d_ws;
        prep_kernel<<<dim3(13312), 256, 0, stream>>>(q, k, v, mask, ws);
        attn_bf16_kernel<<<dim3(TQ_ / 16, B_), 256, 0, stream>>>(ws, out, attn);
    } else {
        attn_fallback_kernel<<<dim3(TQ_ / 16, B_), 256, 0, stream>>>(q, k, v, mask, out, attn);
    }
}